// Round 2
// 1057.702 us; speedup vs baseline: 1.1942x; 1.1942x over previous
//
#include <hip/hip_runtime.h>

// GCNStoModel_MultiHead: 2-layer GraphSAGE-GCN + linear head.
// IN=128, HID=256, OUT=256, PHEAD=64
// N0=1048576, E0=2097152, ND0=131072, E1=131072, ND1=8192, task_index=0.
//
// R1: CSR build + gather aggregation (no float atomics).
// R2: agg latency fix — cooperative edge-index load + __shfl broadcast +
//     8-deep software-pipelined gathers.
// R3: dead-row elimination. Only h1 rows referenced by layer 1
//     (src1 u [0,ND1)) are ever consumed (~66% of ND0). Build a needed-mask
//     + rank (exclusive scan), skip unneeded rows in hist0/fill0/agg0, and
//     compact neigh0/deg0/h1 by rank so gemm1 runs over ~86K rows instead of
//     131K. edge_src1 stores rank[src1[e]]; ranks of rows < ND1 are identity
//     so the layer-1 self-feature path is unchanged. Surviving rows are
//     bitwise identical to R2.
// R3b: fix compile error — a trailing backslash in a comment spliced the
//     `needed` declaration into the previous line's comment.

#define GEMM_BM 64
#define GEMM_BN 64
#define GEMM_BK 32

// ---------------------------------------------------------------------------
// needed[i]=1 for i<ND1 and for every i in src1. (benign write races)
__global__ __launch_bounds__(256) void mark_kernel(const int* __restrict__ src1,
                                                   int* __restrict__ needed,
                                                   int E, int nd1) {
    int e = blockIdx.x * 256 + threadIdx.x;
    if (e < nd1) needed[e] = 1;
    if (e >= E) return;
    needed[src1[e]] = 1;
}

// CSR build step 1: count[d] = #edges with dst==d   (count pre-zeroed)
// R3: rows with needed==0 are skipped entirely (their CSR row stays empty).
__global__ __launch_bounds__(256) void hist_kernel(const int* __restrict__ dst,
                                                   const int* __restrict__ needed,
                                                   int* __restrict__ count, int E) {
    int e = blockIdx.x * 256 + threadIdx.x;
    if (e >= E) return;
    int d = dst[e];
    if (needed != nullptr && needed[d] == 0) return;
    atomicAdd(&count[d], 1);
}

// CSR build step 2a: per-block (1024-elem) sums
__global__ __launch_bounds__(256) void block_sum_kernel(const int* __restrict__ count,
                                                        int* __restrict__ bsum) {
    __shared__ int sdata[256];
    int t = threadIdx.x;
    int i = blockIdx.x * 1024 + t * 4;
    int s = count[i] + count[i + 1] + count[i + 2] + count[i + 3];
    sdata[t] = s;
    __syncthreads();
    for (int off = 128; off > 0; off >>= 1) {
        if (t < off) sdata[t] += sdata[t + off];
        __syncthreads();
    }
    if (t == 0) bsum[blockIdx.x] = sdata[0];
}

// CSR build step 2b: exclusive scan of nb block sums (nb <= 256), one block.
// R3: optionally writes the grand total (= compacted row count) to *total.
__global__ __launch_bounds__(256) void scan_small_kernel(const int* __restrict__ bsum,
                                                         int* __restrict__ boff, int nb,
                                                         int* __restrict__ total) {
    __shared__ int sdata[256];
    int t = threadIdx.x;
    int v = (t < nb) ? bsum[t] : 0;
    sdata[t] = v;
    __syncthreads();
    int val = v;
    for (int off = 1; off < 256; off <<= 1) {
        int x = (t >= off) ? sdata[t - off] : 0;
        __syncthreads();
        val += x;
        sdata[t] = val;
        __syncthreads();
    }
    if (t < nb) boff[t] = val - v;  // exclusive
    if (total != nullptr && t == nb - 1) *total = val;
}

// CSR build step 2c: final exclusive scan -> row_start (and cursor copy)
__global__ __launch_bounds__(256) void scan_final_kernel(const int* __restrict__ count,
                                                         const int* __restrict__ boff,
                                                         int* __restrict__ row_start,
                                                         int* __restrict__ cursor) {
    __shared__ int sdata[256];
    int t = threadIdx.x;
    int base_i = blockIdx.x * 1024 + t * 4;
    int c0 = count[base_i], c1 = count[base_i + 1], c2 = count[base_i + 2], c3 = count[base_i + 3];
    int local = c0 + c1 + c2 + c3;
    sdata[t] = local;
    __syncthreads();
    int val = local;
    for (int off = 1; off < 256; off <<= 1) {
        int x = (t >= off) ? sdata[t - off] : 0;
        __syncthreads();
        val += x;
        sdata[t] = val;
        __syncthreads();
    }
    int base = boff[blockIdx.x] + (val - local);  // exclusive prefix
    int r0 = base, r1 = r0 + c0, r2 = r1 + c1, r3 = r2 + c2;
    row_start[base_i] = r0; row_start[base_i + 1] = r1;
    row_start[base_i + 2] = r2; row_start[base_i + 3] = r3;
    cursor[base_i] = r0; cursor[base_i + 1] = r1;
    cursor[base_i + 2] = r2; cursor[base_i + 3] = r3;
}

// CSR build step 3: bucket edges by dst.
// R3: skip unneeded dst rows; optionally store remap[src] (rank) instead of src.
__global__ __launch_bounds__(256) void fill_kernel(const int* __restrict__ src,
                                                   const int* __restrict__ dst,
                                                   const int* __restrict__ needed,
                                                   const int* __restrict__ remap,
                                                   int* __restrict__ cursor,
                                                   int* __restrict__ edge_src, int E) {
    int e = blockIdx.x * 256 + threadIdx.x;
    if (e >= E) return;
    int d = dst[e];
    if (needed != nullptr && needed[d] == 0) return;
    int s = src[e];
    if (remap != nullptr) s = remap[s];
    int p = atomicAdd(&cursor[d], 1);
    edge_src[p] = s;
}

// ---------------------------------------------------------------------------
// gather aggregation: one wave per dst row; row held in registers (RF floats
// per lane, K = 64*RF). neigh[out_r] = selff[w] + sum_{e in row w} feat[src[e]];
// deg[out_r] = count[w] + 1.
// COMPACT: skip rows with needed==0 and write outputs at rank[w].
template<int RF> struct VecSel;
template<> struct VecSel<2> { using V = float2; };
template<> struct VecSel<4> { using V = float4; };

template<int RF, bool COMPACT>
__global__ __launch_bounds__(256) void agg_kernel(const float* __restrict__ feat,
                                                  const float* __restrict__ selff,
                                                  const int* __restrict__ row_start,
                                                  const int* __restrict__ count,
                                                  const int* __restrict__ edge_src,
                                                  const int* __restrict__ needed,
                                                  const int* __restrict__ rank,
                                                  float* __restrict__ neigh,
                                                  float* __restrict__ deg, int ND) {
    using V = typename VecSel<RF>::V;
    int w = (blockIdx.x * 256 + threadIdx.x) >> 6;  // wave id == dst row
    int lane = threadIdx.x & 63;
    if (w >= ND) return;
    int out_r = w;
    if constexpr (COMPACT) {
        if (needed[w] == 0) return;
        out_r = rank[w];
    }
    const int K = 64 * RF;
    size_t lo_in  = (size_t)w * K + (size_t)lane * RF;
    size_t lo_out = (size_t)out_r * K + (size_t)lane * RF;
    V acc = *(const V*)(selff + lo_in);
    const int rs = row_start[w];
    const int cnt = count[w];

    for (int base = 0; base < cnt; base += 64) {
        const int rem = min(cnt - base, 64);                 // >= 1
        // cooperative, coalesced index load (clamped; mask fixes validity)
        const int idx = edge_src[rs + base + min(lane, rem - 1)];

        for (int jj = 0; jj < rem; jj += 8) {
            int s[8];
            float m[8];
            #pragma unroll
            for (int k = 0; k < 8; ++k) {
                int j = jj + k;
                s[k] = __shfl(idx, min(j, rem - 1));
                m[k] = (j < rem) ? 1.0f : 0.0f;
            }
            V v[8];
            #pragma unroll
            for (int k = 0; k < 8; ++k)
                v[k] = *(const V*)(feat + (size_t)s[k] * K + (size_t)lane * RF);
            #pragma unroll
            for (int k = 0; k < 8; ++k) {
                acc.x += v[k].x * m[k];
                acc.y += v[k].y * m[k];
                if constexpr (RF == 4) {
                    acc.z += v[k].z * m[k];
                    acc.w += v[k].w * m[k];
                }
            }
        }
    }
    *(V*)(neigh + lo_out) = acc;
    if (lane == 0) deg[out_r] = (float)(cnt + 1);
}

// ---------------------------------------------------------------------------
// C[M,N] = act( (A * rowscale) @ W^T + b ), fp32, 64x64x32 tiles, 4x4/thread.
// DYNM: M is read from *m_ptr at runtime; blocks fully past M exit early.
// The last partial tile computes garbage pad rows (in-bounds reads) that are
// never consumed downstream.
template<bool RELU, bool HAS_RS, bool DYNM>
__global__ __launch_bounds__(256) void gemm_kernel(const float* __restrict__ A,    // M x K
                                                   const float* __restrict__ deg,  // M or null
                                                   const float* __restrict__ W,    // N x K
                                                   const float* __restrict__ bias, // N
                                                   float* __restrict__ C,          // M x N
                                                   const int* __restrict__ m_ptr,
                                                   int N, int K) {
    __shared__ float As[GEMM_BK][GEMM_BM];  // [k][m]
    __shared__ float Ws[GEMM_BK][GEMM_BN];  // [k][n]

    const int t = threadIdx.x;
    const int row0 = blockIdx.x * GEMM_BM;
    if constexpr (DYNM) {
        if (row0 >= *m_ptr) return;
    }
    const int col0 = blockIdx.y * GEMM_BN;

    const int tm = (t & 15) * 4;
    const int tn = (t >> 4) * 4;

    float acc[4][4] = {};

    const int lr = t >> 3;       // 0..31
    const int lk = (t & 7) * 4;  // 0,4,...,28

    for (int k0 = 0; k0 < K; k0 += GEMM_BK) {
        #pragma unroll
        for (int pass = 0; pass < 2; ++pass) {
            int r = lr + pass * 32;
            const float4 v = *(const float4*)(A + (size_t)(row0 + r) * K + k0 + lk);
            As[lk + 0][r] = v.x; As[lk + 1][r] = v.y;
            As[lk + 2][r] = v.z; As[lk + 3][r] = v.w;
        }
        #pragma unroll
        for (int pass = 0; pass < 2; ++pass) {
            int n = lr + pass * 32;
            const float4 v = *(const float4*)(W + (size_t)(col0 + n) * K + k0 + lk);
            Ws[lk + 0][n] = v.x; Ws[lk + 1][n] = v.y;
            Ws[lk + 2][n] = v.z; Ws[lk + 3][n] = v.w;
        }
        __syncthreads();

        #pragma unroll
        for (int k = 0; k < GEMM_BK; ++k) {
            const float4 a = *(const float4*)&As[k][tm];
            const float4 w = *(const float4*)&Ws[k][tn];
            acc[0][0] += a.x * w.x; acc[0][1] += a.x * w.y; acc[0][2] += a.x * w.z; acc[0][3] += a.x * w.w;
            acc[1][0] += a.y * w.x; acc[1][1] += a.y * w.y; acc[1][2] += a.y * w.z; acc[1][3] += a.y * w.w;
            acc[2][0] += a.z * w.x; acc[2][1] += a.z * w.y; acc[2][2] += a.z * w.z; acc[2][3] += a.z * w.w;
            acc[3][0] += a.w * w.x; acc[3][1] += a.w * w.y; acc[3][2] += a.w * w.z; acc[3][3] += a.w * w.w;
        }
        __syncthreads();
    }

    float scl[4];
    #pragma unroll
    for (int i = 0; i < 4; ++i)
        scl[i] = HAS_RS ? (1.0f / deg[row0 + tm + i]) : 1.0f;

    float bb[4];
    #pragma unroll
    for (int j = 0; j < 4; ++j) bb[j] = bias[col0 + tn + j];

    #pragma unroll
    for (int i = 0; i < 4; ++i) {
        float4 v;
        v.x = acc[i][0] * scl[i] + bb[0];
        v.y = acc[i][1] * scl[i] + bb[1];
        v.z = acc[i][2] * scl[i] + bb[2];
        v.w = acc[i][3] * scl[i] + bb[3];
        if (RELU) {
            v.x = fmaxf(v.x, 0.0f); v.y = fmaxf(v.y, 0.0f);
            v.z = fmaxf(v.z, 0.0f); v.w = fmaxf(v.w, 0.0f);
        }
        *(float4*)(C + (size_t)(row0 + tm + i) * N + col0 + tn) = v;
    }
}

// ---------------------------------------------------------------------------
extern "C" void kernel_launch(void* const* d_in, const int* in_sizes, int n_in,
                              void* d_out, int out_size, void* d_ws, size_t ws_size,
                              hipStream_t stream) {
    const float* x   = (const float*)d_in[0];
    const int* src0  = (const int*)d_in[1];
    const int* dst0  = (const int*)d_in[2];
    const int* src1  = (const int*)d_in[3];
    const int* dst1  = (const int*)d_in[4];
    const float* W1  = (const float*)d_in[5];
    const float* b1  = (const float*)d_in[6];
    const float* W2  = (const float*)d_in[7];
    const float* b2  = (const float*)d_in[8];
    const float* Wh  = (const float*)d_in[9];
    const float* bh  = (const float*)d_in[10];

    const int E0 = in_sizes[1];
    const int E1 = in_sizes[3];
    const int IN = 128, HID = 256, OUT = 256, PHEAD = 64;
    const int ND0 = 131072, ND1 = 8192;

    // ---- workspace layout (non-overlapping; ~220 MB of the ws) ----
    float* ws = (float*)d_ws;
    float* neigh0c = ws;                               // ND0*IN  (worst case)
    float* deg0c   = neigh0c + (size_t)ND0 * IN;       // ND0
    float* h1c     = deg0c + ND0;                      // ND0*HID (worst case)
    float* neigh1  = h1c + (size_t)ND0 * HID;          // ND1*HID
    float* deg1    = neigh1 + (size_t)ND1 * HID;       // ND1
    float* h2      = deg1 + ND1;                       // ND1*OUT
    float* out     = (float*)d_out;                    // ND1*PHEAD

    // count0, needed, count1 are contiguous and zeroed in ONE memset
    int* count0     = (int*)(h2 + (size_t)ND1 * OUT);  // ND0
    int* needed     = count0 + ND0;                    // ND0
    int* count1     = needed + ND0;                    // ND1
    int* rank       = count1 + ND1;                    // ND0
    int* row_start0 = rank + ND0;                      // ND0
    int* cursor0    = row_start0 + ND0;                // ND0
    int* edge_src0  = cursor0 + ND0;                   // E0
    int* row_start1 = edge_src0 + E0;                  // ND1
    int* cursor1    = row_start1 + ND1;                // ND1
    int* edge_src1  = cursor1 + ND1;                   // E1
    int* bsumA      = edge_src1 + E1;                  // 256 (rank scan)
    int* boffA      = bsumA + 256;                     // 256
    int* bsumB      = boffA + 256;                     // 256 (CSR scans)
    int* boffB      = bsumB + 256;                     // 256
    int* nr_ptr     = boffB + 256;                     // 1: compacted row count

    // ---- zero count0 + needed + count1 in a single memset ----
    hipMemsetAsync(count0, 0, (size_t)(2 * ND0 + ND1) * sizeof(int), stream);

    // ---- needed-mask + rank (exclusive scan over ND0) ----
    mark_kernel<<<E1 / 256, 256, 0, stream>>>(src1, needed, E1, ND1);
    block_sum_kernel<<<ND0 / 1024, 256, 0, stream>>>(needed, bsumA);
    scan_small_kernel<<<1, 256, 0, stream>>>(bsumA, boffA, ND0 / 1024, nr_ptr);
    scan_final_kernel<<<ND0 / 1024, 256, 0, stream>>>(needed, boffA, rank, rank);

    // ---- layer 0: CSR build (needed rows only) + gather aggregate ----
    hist_kernel<<<E0 / 256, 256, 0, stream>>>(dst0, needed, count0, E0);
    block_sum_kernel<<<ND0 / 1024, 256, 0, stream>>>(count0, bsumB);
    scan_small_kernel<<<1, 256, 0, stream>>>(bsumB, boffB, ND0 / 1024, nullptr);
    scan_final_kernel<<<ND0 / 1024, 256, 0, stream>>>(count0, boffB, row_start0, cursor0);
    fill_kernel<<<E0 / 256, 256, 0, stream>>>(src0, dst0, needed, nullptr,
                                              cursor0, edge_src0, E0);
    agg_kernel<2, true><<<ND0 / 4, 256, 0, stream>>>(x, x, row_start0, count0, edge_src0,
                                                     needed, rank, neigh0c, deg0c, ND0);
    {
        // dynamic M (= *nr_ptr); launch worst-case grid, blocks past M exit early
        dim3 g(ND0 / GEMM_BM, HID / GEMM_BN);
        gemm_kernel<true, true, true><<<g, 256, 0, stream>>>(neigh0c, deg0c, W1, b1, h1c,
                                                             nr_ptr, HID, IN);
    }

    // ---- layer 1 (indices pre-remapped to ranks; rank[d]=d for d<ND1) ----
    hist_kernel<<<E1 / 256, 256, 0, stream>>>(dst1, nullptr, count1, E1);
    block_sum_kernel<<<ND1 / 1024, 256, 0, stream>>>(count1, bsumB);
    scan_small_kernel<<<1, 256, 0, stream>>>(bsumB, boffB, ND1 / 1024, nullptr);
    scan_final_kernel<<<ND1 / 1024, 256, 0, stream>>>(count1, boffB, row_start1, cursor1);
    fill_kernel<<<E1 / 256, 256, 0, stream>>>(src1, dst1, nullptr, rank,
                                              cursor1, edge_src1, E1);
    agg_kernel<4, false><<<ND1 / 4, 256, 0, stream>>>(h1c, h1c, row_start1, count1, edge_src1,
                                                      nullptr, nullptr, neigh1, deg1, ND1);
    {
        dim3 g(ND1 / GEMM_BM, OUT / GEMM_BN);
        gemm_kernel<true, true, false><<<g, 256, 0, stream>>>(neigh1, deg1, W2, b2, h2,
                                                              nullptr, OUT, HID);
    }

    // ---- head ----
    {
        dim3 g(ND1 / GEMM_BM, PHEAD / GEMM_BN);
        gemm_kernel<false, false, false><<<g, 256, 0, stream>>>(h2, nullptr, Wh, bh, out,
                                                                nullptr, PHEAD, OUT);
    }
}